// Round 7
// baseline (710.720 us; speedup 1.0000x reference)
//
#include <hip/hip_runtime.h>
#include <hip/hip_bf16.h>

typedef __attribute__((ext_vector_type(4))) float f32x4;
typedef __attribute__((ext_vector_type(8))) short short8;

__device__ __forceinline__ float bf2f(ushort u) {
    union { unsigned int u; float f; } x; x.u = ((unsigned int)u) << 16; return x.f;
}
__device__ __forceinline__ ushort f2bf(float f) {
    union { float f; unsigned int u; } x; x.f = f;
    unsigned int u = x.u;
    unsigned int r = (u + 0x7fffu + ((u >> 16) & 1u)) >> 16;  // RNE
    return (ushort)r;
}

// ---------------------------------------------------------------------------
// k_prep: grid 257.  Blocks 0..255 (= o): recompute masks locally, write
// Wa[a][o][t*256+i] = bf16(m[a][t]*conv_w[o][i][t]).  Block 256: zero cnt +
// loss/acc, then bucket sample ids by action for all 3 steps.
// ---------------------------------------------------------------------------
__global__ __launch_bounds__(256) void k_prep(
    const float* __restrict__ conv_w, const float* __restrict__ a_table,
    const float* __restrict__ a_W, const float* __restrict__ a_b,
    const int* __restrict__ actions, int* __restrict__ cnt,
    int* __restrict__ list, ushort* __restrict__ Wa,
    float* __restrict__ out_head)
{
    __shared__ float ao[4][9];
    __shared__ float m[4][9];
    const int bid = blockIdx.x, tid = threadIdx.x;
    if (bid < 256) {
        if (tid < 36) {
            const int a = tid / 9, t = tid % 9;
            float s = a_b[t];
            for (int c = 0; c < 32; c++) s += a_table[a * 32 + c] * a_W[t * 32 + c];
            ao[a][t] = s;
        }
        __syncthreads();
        if (tid < 4) {
            float mx = -1e30f;
            for (int t = 0; t < 9; t++) mx = fmaxf(mx, ao[tid][t]);
            float e[9], z = 0.f;
            for (int t = 0; t < 9; t++) { e[t] = expf(ao[tid][t] - mx); z += e[t]; }
            for (int t = 0; t < 9; t++) m[tid][t] = e[t] / z;
        }
        __syncthreads();
        const int o = bid;
        float w9[9];
        #pragma unroll
        for (int t = 0; t < 9; t++) w9[t] = conv_w[(o * 256 + tid) * 9 + t];
        #pragma unroll
        for (int a = 0; a < 4; a++)
            #pragma unroll
            for (int t = 0; t < 9; t++)
                Wa[(size_t)((a << 8) + o) * 2304 + t * 256 + tid] = f2bf(m[a][t] * w9[t]);
    } else {
        if (tid < 12) cnt[tid] = 0;
        if (tid == 0) { out_head[0] = 0.f; out_head[1] = 0.f; }
        __syncthreads();
        for (int it = 0; it < 24; it++) {
            const int idx = it * 256 + tid;          // 0..6143
            const int jj = idx >> 11, b = idx & 2047;
            const int av = actions[b * 3 + jj];
            const int pos = atomicAdd(&cnt[jj * 4 + av], 1);
            list[((jj * 4 + av) << 11) + pos] = b;
        }
    }
}

// ---------------------------------------------------------------------------
// k_lemb: grid B=2048, 256 thr (e).  c0[b][p][e] = bf16(sum_k map[idx][e]),
// idx==0 contributes 0.
// ---------------------------------------------------------------------------
__global__ __launch_bounds__(256) void k_lemb(
    const float* __restrict__ mapt, const int* __restrict__ lms,
    ushort* __restrict__ c0)
{
    const int b = blockIdx.x, e = threadIdx.x;
    for (int p = 0; p < 16; p++) {
        const int* lm = lms + (b * 16 + p) * 8;
        float s = 0.f;
        #pragma unroll
        for (int k = 0; k < 8; k++) {
            const int idx = lm[k];
            if (idx) s += mapt[idx * 256 + e];
        }
        c0[(size_t)(b * 16 + p) * 256 + e] = f2bf(s);
    }
}

// ---------------------------------------------------------------------------
// k_conv v3: BARRIER-FREE, LDS-FREE.  BM=128 (om half), BN=128 (8 same-action
// samples), 4 waves (2M x 2N), wave tile 64x64, K-step 32.  A and B stream
// global -> registers -> MFMA with ping-pong prefetch; no __syncthreads in
// the whole kernel, so waves slip freely and the compiler emits counted
// vmcnt (no drain).  Wa is L2-resident (4.7 MB); B slabs are L1/L2-resident.
// Grid 520 = 2 om-halves x 260 groups, XCD-chunk swizzled (8 x 65).
// ---------------------------------------------------------------------------
__global__ __launch_bounds__(256, 2) void k_conv(
    const ushort* __restrict__ cur, const ushort* __restrict__ Wa,
    const int* __restrict__ cnt, const int* __restrict__ list,
    const int j, ushort* __restrict__ outp)
{
    const int tid = threadIdx.x;

    const int c0n = cnt[j * 4 + 0], c1n = cnt[j * 4 + 1],
              c2n = cnt[j * 4 + 2], c3n = cnt[j * 4 + 3];
    const int t0 = (c0n + 7) >> 3;
    const int t1 = t0 + ((c1n + 7) >> 3);
    const int t2 = t1 + ((c2n + 7) >> 3);
    const int t3 = t2 + ((c3n + 7) >> 3);
    const int bid = blockIdx.x;
    const int wg2 = (bid & 7) * 65 + (bid >> 3);        // bijective: 520 = 8*65
    const int om  = wg2 >= 260 ? 1 : 0;
    const int g   = wg2 - om * 260;
    if (g >= t3) return;                  // no barriers anywhere -> safe exit
    int a, off, ca;
    if      (g < t0) { a = 0; off = 0;  ca = c0n; }
    else if (g < t1) { a = 1; off = t0; ca = c1n; }
    else if (g < t2) { a = 2; off = t1; ca = c2n; }
    else             { a = 3; off = t2; ca = c3n; }
    const int slot0 = (g - off) * 8;
    const int* la = list + ((j * 4 + a) << 11);

    const int wid = tid >> 6, lane = tid & 63;
    const int l15 = lane & 15, l4 = lane >> 4;
    const int wm = wid >> 1, wn = wid & 1;

    int sid[4]; bool vst[4];
    #pragma unroll
    for (int nf = 0; nf < 4; nf++) {
        const int sl = slot0 + wn * 4 + nf;
        vst[nf] = sl < ca;
        sid[nf] = vst[nf] ? la[sl] : 0;
    }

    // per-lane A base: row o = a*256 + om*128 + wm*64 + (mf*16) + l15
    const ushort* abase =
        Wa + (size_t)((a << 8) + om * 128 + wm * 64 + l15) * 2304 + l4 * 8;
    const ushort* bs[4];
    #pragma unroll
    for (int nf = 0; nf < 4; nf++)
        bs[nf] = cur + (size_t)sid[nf] * 4096 + l4 * 8;

    const int ph = l15 >> 2, pw = l15 & 3;
    const short8 bzero = {0, 0, 0, 0, 0, 0, 0, 0};

    f32x4 acc[4][4];
    #pragma unroll
    for (int mf = 0; mf < 4; mf++)
        #pragma unroll
        for (int nf = 0; nf < 4; nf++) acc[mf][nf] = (f32x4){0.f, 0.f, 0.f, 0.f};

    short8 A0[4], B0[4], A1[4], B1[4];

    // A loader: 4 x 16B per lane (ks may overrun to 72: +1 row, allocated)
    #define LOADA(d, ks)                                                       \
        _Pragma("unroll")                                                      \
        for (int mf = 0; mf < 4; mf++)                                         \
            d[mf] = *(const short8*)(abase + mf * 36864 + (ks) * 32);
    // B loader: shift/pad/select per t = ks>>3 (ks=72 -> t=9, partial junk,
    // never consumed; addresses stay in allocated ws)
    #define LOADB(d, ks)                                                       \
        {                                                                      \
            const int tn = (ks) >> 3, i0b = ((ks) & 7) * 32;                   \
            const int td = (tn * 11) >> 5;      /* tn/3 for tn<=9 */           \
            const int tm = tn - 3 * td;                                        \
            const int hh = ph + td - 1, ww = pw + tm - 1;                      \
            const bool xv = (hh >= 0) & (hh < 4) & (ww >= 0) & (ww < 4);       \
            const int po = ((hh << 2) + ww) * 256 + i0b;                       \
            _Pragma("unroll")                                                  \
            for (int nf = 0; nf < 4; nf++)                                     \
                d[nf] = xv ? *(const short8*)(bs[nf] + po) : bzero;            \
        }
    #define MFMA16(Af, Bf)                                                     \
        _Pragma("unroll")                                                      \
        for (int mf = 0; mf < 4; mf++)                                         \
            _Pragma("unroll")                                                  \
            for (int nf = 0; nf < 4; nf++)                                     \
                acc[mf][nf] = __builtin_amdgcn_mfma_f32_16x16x32_bf16(         \
                    Af[mf], Bf[nf], acc[mf][nf], 0, 0, 0);

    LOADA(A0, 0); LOADB(B0, 0);
    for (int ks = 0; ks < 72; ks += 2) {
        LOADA(A1, ks + 1); LOADB(B1, ks + 1);
        MFMA16(A0, B0);
        LOADA(A0, ks + 2); LOADB(B0, ks + 2);   // ks=70 -> 72 overrun, safe
        MFMA16(A1, B1);
    }

    // epilogue: C frag col=l15 (=p), row=l4*4+r (=o within 16-tile)
    #pragma unroll
    for (int nf = 0; nf < 4; nf++) {
        if (!vst[nf]) continue;                      // wave-uniform branch
        const size_t rowb = ((size_t)sid[nf] * 16 + l15) * 256;
        #pragma unroll
        for (int mf = 0; mf < 4; mf++) {
            const int ob = om * 128 + wm * 64 + mf * 16 + l4 * 4;
            ushort o4[4];
            #pragma unroll
            for (int r = 0; r < 4; r++) o4[r] = f2bf(acc[mf][nf][r]);
            *(uint2*)&outp[rowb + ob] = *(const uint2*)o4;
        }
    }
    #undef LOADA
    #undef LOADB
    #undef MFMA16
}

// ---------------------------------------------------------------------------
// k_final: grid B=2048.  emb in-block (17-padded LDS rows, conflict-free),
// vectorized bf16 dot (uint4 loads), softmax chain, loss/acc atomics.
// ---------------------------------------------------------------------------
__global__ __launch_bounds__(256) void k_final(
    const ushort* __restrict__ c0, const ushort* __restrict__ c1,
    const ushort* __restrict__ c2, const ushort* __restrict__ c3,
    const float* __restrict__ gold, const int* __restrict__ gs,
    const int* __restrict__ y, float* __restrict__ d_out)
{
    __shared__ float embl[4][272];   // 16 rows x 17 floats per s (pad kills conflicts)
    __shared__ float red[256];
    __shared__ float lg[16];
    const int b = blockIdx.x, tid = threadIdx.x;
    {
        const int s = tid >> 6, e0 = (tid & 63) * 4;
        const int* g = gs + b * 64 + s * 16;
        float4 accv = make_float4(0.f, 0.f, 0.f, 0.f);
        #pragma unroll
        for (int l = 0; l < 16; l++) {
            const float4 v = *(const float4*)&gold[g[l] * 256 + e0];
            accv.x += v.x; accv.y += v.y; accv.z += v.z; accv.w += v.w;
        }
        float* dst = &embl[s][(e0 >> 4) * 17 + (e0 & 15)];
        dst[0] = accv.x; dst[1] = accv.y; dst[2] = accv.z; dst[3] = accv.w;
    }
    __syncthreads();
    const int p = tid >> 4, g16 = tid & 15;
    const ushort* rows[4] = {
        c0 + (size_t)(b * 16 + p) * 256, c1 + (size_t)(b * 16 + p) * 256,
        c2 + (size_t)(b * 16 + p) * 256, c3 + (size_t)(b * 16 + p) * 256 };
    float acc = 0.f;
    #pragma unroll
    for (int s = 0; s < 4; s++) {
        const ushort* row = rows[s] + g16 * 16;
        const uint4 v0 = *(const uint4*)row;
        const uint4 v1 = *(const uint4*)(row + 8);
        const ushort* pv0 = (const ushort*)&v0;
        const ushort* pv1 = (const ushort*)&v1;
        const float* eb = &embl[s][g16 * 17];
        #pragma unroll
        for (int q = 0; q < 8; q++) acc += bf2f(pv0[q]) * eb[q];
        #pragma unroll
        for (int q = 0; q < 8; q++) acc += bf2f(pv1[q]) * eb[8 + q];
    }
    red[tid] = acc;
    __syncthreads();
    for (int st = 8; st >= 1; st >>= 1) {
        if (g16 < st) red[tid] += red[tid + st];
        __syncthreads();
    }
    if (g16 == 0) lg[p] = red[tid];
    __syncthreads();
    if (tid == 0) {
        float mx = -1e30f;
        for (int q = 0; q < 16; q++) mx = fmaxf(mx, lg[q]);
        float ex[16], z = 0.f;
        for (int q = 0; q < 16; q++) { ex[q] = expf(lg[q] - mx); z += ex[q]; }
        float prob[16];
        for (int q = 0; q < 16; q++) {
            prob[q] = ex[q] / z;
            d_out[2 + b * 16 + q] = prob[q];
        }
        int am = 0; float bv = prob[0];
        for (int q = 1; q < 16; q++) if (prob[q] > bv) { bv = prob[q]; am = q; }
        const int yt = y[b * 2] * 4 + y[b * 2 + 1];
        float z2 = 0.f;
        for (int q = 0; q < 16; q++) z2 += expf(prob[q]);
        const float logp = prob[yt] - logf(z2);
        atomicAdd(&d_out[0], -logp * (1.0f / 2048.0f));
        atomicAdd(&d_out[1], (am == yt) ? (1.0f / 2048.0f) : 0.0f);
    }
}

// ---------------------------------------------------------------------------
extern "C" void kernel_launch(void* const* d_in, const int* in_sizes, int n_in,
                              void* d_out, int out_size, void* d_ws, size_t ws_size,
                              hipStream_t stream) {
    const float* gold_table = (const float*)d_in[0];   // (11,256)
    const float* map_table  = (const float*)d_in[1];   // (128,256)
    const float* conv_w     = (const float*)d_in[2];   // (256,256,3,3)
    const float* a_table    = (const float*)d_in[3];   // (4,32)
    const float* a_W        = (const float*)d_in[4];   // (9,32)
    const float* a_b        = (const float*)d_in[5];   // (9,)
    const int*   gs         = (const int*)d_in[6];     // (2048,4,16)
    const int*   actions    = (const int*)d_in[7];     // (2048,3)
    const int*   lms        = (const int*)d_in[8];     // (2048,4,4,8)
    const int*   y          = (const int*)d_in[9];     // (2048,2)
    float* out = (float*)d_out;

    char* ws = (char*)d_ws;
    int*    cnt  = (int*)(ws + 0);                     // 48 B
    int*    list = (int*)(ws + 256);                   // 98,304 B
    ushort* Wa   = (ushort*)(ws + 131072);             // 4,718,592 B
    ushort* c0   = (ushort*)(ws + 4849664);            // 16,777,216 B each
    ushort* c1   = (ushort*)(ws + 21626880);
    ushort* c2   = (ushort*)(ws + 38404096);
    ushort* c3   = (ushort*)(ws + 55181312);           // end 71,958,528
    (void)in_sizes; (void)n_in; (void)out_size; (void)ws_size;

    k_prep <<<257, 256, 0, stream>>>(conv_w, a_table, a_W, a_b, actions,
                                     cnt, list, Wa, out);
    k_lemb <<<2048, 256, 0, stream>>>(map_table, lms, c0);
    k_conv <<<520, 256, 0, stream>>>(c0, Wa, cnt, list, 0, c1);
    k_conv <<<520, 256, 0, stream>>>(c1, Wa, cnt, list, 1, c2);
    k_conv <<<520, 256, 0, stream>>>(c2, Wa, cnt, list, 2, c3);
    k_final<<<2048, 256, 0, stream>>>(c0, c1, c2, c3, gold_table, gs, y, out);
}

// Round 8
// 708.124 us; speedup vs baseline: 1.0037x; 1.0037x over previous
//
#include <hip/hip_runtime.h>
#include <hip/hip_bf16.h>

typedef __attribute__((ext_vector_type(4))) float f32x4;
typedef __attribute__((ext_vector_type(8))) short short8;

__device__ __forceinline__ float bf2f(ushort u) {
    union { unsigned int u; float f; } x; x.u = ((unsigned int)u) << 16; return x.f;
}
__device__ __forceinline__ ushort f2bf(float f) {
    union { float f; unsigned int u; } x; x.f = f;
    unsigned int u = x.u;
    unsigned int r = (u + 0x7fffu + ((u >> 16) & 1u)) >> 16;  // RNE
    return (ushort)r;
}

// ---------------------------------------------------------------------------
// k_prep: grid 257.  Blocks 0..255 (= o): recompute masks locally, write
// Wa[a][o][t*256+i] = bf16(m[a][t]*conv_w[o][i][t]).  Block 256: zero cnt +
// loss/acc, then bucket sample ids by action for all 3 steps.
// ---------------------------------------------------------------------------
__global__ __launch_bounds__(256) void k_prep(
    const float* __restrict__ conv_w, const float* __restrict__ a_table,
    const float* __restrict__ a_W, const float* __restrict__ a_b,
    const int* __restrict__ actions, int* __restrict__ cnt,
    int* __restrict__ list, ushort* __restrict__ Wa,
    float* __restrict__ out_head)
{
    __shared__ float ao[4][9];
    __shared__ float m[4][9];
    const int bid = blockIdx.x, tid = threadIdx.x;
    if (bid < 256) {
        if (tid < 36) {
            const int a = tid / 9, t = tid % 9;
            float s = a_b[t];
            for (int c = 0; c < 32; c++) s += a_table[a * 32 + c] * a_W[t * 32 + c];
            ao[a][t] = s;
        }
        __syncthreads();
        if (tid < 4) {
            float mx = -1e30f;
            for (int t = 0; t < 9; t++) mx = fmaxf(mx, ao[tid][t]);
            float e[9], z = 0.f;
            for (int t = 0; t < 9; t++) { e[t] = expf(ao[tid][t] - mx); z += e[t]; }
            for (int t = 0; t < 9; t++) m[tid][t] = e[t] / z;
        }
        __syncthreads();
        const int o = bid;
        float w9[9];
        #pragma unroll
        for (int t = 0; t < 9; t++) w9[t] = conv_w[(o * 256 + tid) * 9 + t];
        #pragma unroll
        for (int a = 0; a < 4; a++)
            #pragma unroll
            for (int t = 0; t < 9; t++)
                Wa[(size_t)((a << 8) + o) * 2304 + t * 256 + tid] = f2bf(m[a][t] * w9[t]);
    } else {
        if (tid < 12) cnt[tid] = 0;
        if (tid == 0) { out_head[0] = 0.f; out_head[1] = 0.f; }
        __syncthreads();
        for (int it = 0; it < 24; it++) {
            const int idx = it * 256 + tid;          // 0..6143
            const int jj = idx >> 11, b = idx & 2047;
            const int av = actions[b * 3 + jj];
            const int pos = atomicAdd(&cnt[jj * 4 + av], 1);
            list[((jj * 4 + av) << 11) + pos] = b;
        }
    }
}

// ---------------------------------------------------------------------------
// k_lemb: grid B=2048, 256 thr.  Wave w handles p=4w..4w+3 (lm scalarizes);
// float4 gathers of map_table rows, bf16x4 stores.
// ---------------------------------------------------------------------------
__global__ __launch_bounds__(256) void k_lemb(
    const float* __restrict__ mapt, const int* __restrict__ lms,
    ushort* __restrict__ c0)
{
    const int b = blockIdx.x, tid = threadIdx.x;
    const int e4 = (tid & 63) * 4, pw = tid >> 6;
    #pragma unroll
    for (int pp = 0; pp < 4; ++pp) {
        const int p = pw * 4 + pp;
        const int* lm = lms + (b * 16 + p) * 8;
        float4 s = make_float4(0.f, 0.f, 0.f, 0.f);
        #pragma unroll
        for (int k = 0; k < 8; ++k) {
            const int idx = lm[k];
            if (idx) {
                const float4 v = *(const float4*)&mapt[idx * 256 + e4];
                s.x += v.x; s.y += v.y; s.z += v.z; s.w += v.w;
            }
        }
        ushort o4[4] = { f2bf(s.x), f2bf(s.y), f2bf(s.z), f2bf(s.w) };
        *(uint2*)&c0[(size_t)(b * 16 + p) * 256 + e4] = *(const uint2*)o4;
    }
}

// ---------------------------------------------------------------------------
// k_conv v4: B-in-LDS (staged ONCE, one barrier total), A streamed
// global->reg with depth-1 ping-pong (L2-hit via action->XCD binding).
// Grid 4096 = 8 xcd-slots x 512 groups; slot = bid&7 -> (action = bid&3,
// om = (bid>>2)&1); round-robin bid->XCD puts one action-half of Wa
// (0.59 MB) per XCD L2.  BM=128 (om), BN=64 (4 samples), 4 waves (2M x 2N),
// wave tile 64x32, K-step 32.  LDS: 4 samples x 17 rows (row 16 = zeros for
// padding) x 256 bf16, XOR-swizzled chunks (c ^ (row&7)) -> <=2-way banks.
// ---------------------------------------------------------------------------
__global__ __launch_bounds__(256, 4) void k_conv(
    const ushort* __restrict__ cur, const ushort* __restrict__ Wa,
    const int* __restrict__ cnt, const int* __restrict__ list,
    const int j, ushort* __restrict__ outp)
{
    __shared__ __align__(16) ushort Blds[4 * 17 * 256];   // 34,816 B
    const int tid = threadIdx.x, bid = blockIdx.x;
    const int a = bid & 3, om = (bid >> 2) & 1, grp = bid >> 3;
    const int ca = cnt[j * 4 + a];
    if (grp * 4 >= ca) return;            // uniform exit before the barrier
    const int* la = list + ((j * 4 + a) << 11) + grp * 4;

    const int wid = tid >> 6, lane = tid & 63;
    const int l15 = lane & 15, l4 = lane >> 4;
    const int wm = wid >> 1, wn = wid & 1;

    // ---- stage 4 samples into LDS (wave wid -> sample slot wid) ----
    {
        const int sw = (grp * 4 + wid < ca) ? la[wid] : la[0];
        const ushort* src = cur + (size_t)sw * 4096;
        const int p = lane >> 2, cg = lane & 3;
        ushort* dst = Blds + wid * 4352 + p * 256;
        #pragma unroll
        for (int qq = 0; qq < 8; ++qq) {
            const int c = qq * 4 + cg;
            const uint4 v = *(const uint4*)(src + p * 256 + c * 8);
            *(uint4*)(dst + (c ^ (p & 7)) * 8) = v;
        }
        if (lane < 32) {                       // zero row 16 (padding source)
            const short8 z = {0, 0, 0, 0, 0, 0, 0, 0};
            *(short8*)(Blds + wid * 4352 + 16 * 256 + lane * 8) = z;
        }
    }

    int sid[2]; bool vst[2];
    #pragma unroll
    for (int nf = 0; nf < 2; ++nf) {
        const int sl = wn * 2 + nf;
        vst[nf] = (grp * 4 + sl) < ca;
        sid[nf] = vst[nf] ? la[sl] : 0;
    }

    // A base: row o' = a*256 + om*128 + wm*64 + mf*16 + l15, k chunk l4*8
    const ushort* abase =
        Wa + (size_t)((a << 8) + om * 128 + wm * 64 + l15) * 2304 + l4 * 8;

    f32x4 acc[4][2];
    #pragma unroll
    for (int mf = 0; mf < 4; ++mf) {
        acc[mf][0] = (f32x4){0.f, 0.f, 0.f, 0.f};
        acc[mf][1] = (f32x4){0.f, 0.f, 0.f, 0.f};
    }

    const int ph = l15 >> 2, pq = l15 & 3;
    const ushort* b0base = Blds + (wn * 2 + 0) * 4352;
    const ushort* b1base = Blds + (wn * 2 + 1) * 4352;

    short8 Abuf[2][4];
    #pragma unroll
    for (int mf = 0; mf < 4; ++mf)
        Abuf[0][mf] = *(const short8*)(abase + mf * 36864);

    __syncthreads();                       // the ONLY barrier in the kernel

    for (int t = 0; t < 9; ++t) {
        const int td = (t * 11) >> 5, tm = t - td * 3;   // t/3, t%3
        const int hh = ph + td - 1, ww = pq + tm - 1;
        const bool xv = (hh >= 0) & (hh < 4) & (ww >= 0) & (ww < 4);
        const int row = xv ? ((hh << 2) + ww) : 16;      // 16 = zero row
        const int rbase = row * 256, rx = row & 7;
        #pragma unroll
        for (int k8 = 0; k8 < 8; ++k8) {
            const int ks = t * 8 + k8;
            // prefetch next A (ks=71 -> 72 overruns into adjacent ws, unused)
            #pragma unroll
            for (int mf = 0; mf < 4; ++mf)
                Abuf[(k8 + 1) & 1][mf] =
                    *(const short8*)(abase + mf * 36864 + (ks + 1) * 32);
            const int ch = ((k8 * 4 + l4) ^ rx) * 8;
            const short8 bf0 = *(const short8*)(b0base + rbase + ch);
            const short8 bf1 = *(const short8*)(b1base + rbase + ch);
            #pragma unroll
            for (int mf = 0; mf < 4; ++mf) {
                acc[mf][0] = __builtin_amdgcn_mfma_f32_16x16x32_bf16(
                    Abuf[k8 & 1][mf], bf0, acc[mf][0], 0, 0, 0);
                acc[mf][1] = __builtin_amdgcn_mfma_f32_16x16x32_bf16(
                    Abuf[k8 & 1][mf], bf1, acc[mf][1], 0, 0, 0);
            }
        }
    }

    // epilogue: C frag col=l15 (=p), row=l4*4+r (=o within 16-tile)
    #pragma unroll
    for (int nf = 0; nf < 2; ++nf) {
        if (!vst[nf]) continue;                      // wave-uniform branch
        const size_t rowb = ((size_t)sid[nf] * 16 + l15) * 256;
        #pragma unroll
        for (int mf = 0; mf < 4; ++mf) {
            const int ob = om * 128 + wm * 64 + mf * 16 + l4 * 4;
            ushort o4[4];
            #pragma unroll
            for (int r = 0; r < 4; r++) o4[r] = f2bf(acc[mf][nf][r]);
            *(uint2*)&outp[rowb + ob] = *(const uint2*)o4;
        }
    }
}

// ---------------------------------------------------------------------------
// k_final: grid B=2048.  emb in-block (17-padded LDS), vectorized bf16 dot,
// shfl_xor 16-lane reduction (no LDS barrier chain), softmax, loss/acc.
// ---------------------------------------------------------------------------
__global__ __launch_bounds__(256) void k_final(
    const ushort* __restrict__ c0, const ushort* __restrict__ c1,
    const ushort* __restrict__ c2, const ushort* __restrict__ c3,
    const float* __restrict__ gold, const int* __restrict__ gs,
    const int* __restrict__ y, float* __restrict__ d_out)
{
    __shared__ float embl[4][272];
    __shared__ float lg[16];
    const int b = blockIdx.x, tid = threadIdx.x;
    {
        const int s = tid >> 6, e0 = (tid & 63) * 4;
        const int* g = gs + b * 64 + s * 16;
        float4 accv = make_float4(0.f, 0.f, 0.f, 0.f);
        #pragma unroll
        for (int l = 0; l < 16; l++) {
            const float4 v = *(const float4*)&gold[g[l] * 256 + e0];
            accv.x += v.x; accv.y += v.y; accv.z += v.z; accv.w += v.w;
        }
        float* dst = &embl[s][(e0 >> 4) * 17 + (e0 & 15)];
        dst[0] = accv.x; dst[1] = accv.y; dst[2] = accv.z; dst[3] = accv.w;
    }
    __syncthreads();
    const int p = tid >> 4, g16 = tid & 15;
    const ushort* rows[4] = {
        c0 + (size_t)(b * 16 + p) * 256, c1 + (size_t)(b * 16 + p) * 256,
        c2 + (size_t)(b * 16 + p) * 256, c3 + (size_t)(b * 16 + p) * 256 };
    float acc = 0.f;
    #pragma unroll
    for (int s = 0; s < 4; s++) {
        const ushort* row = rows[s] + g16 * 16;
        const uint4 v0 = *(const uint4*)row;
        const uint4 v1 = *(const uint4*)(row + 8);
        const ushort* pv0 = (const ushort*)&v0;
        const ushort* pv1 = (const ushort*)&v1;
        const float* eb = &embl[s][g16 * 17];
        #pragma unroll
        for (int q = 0; q < 8; q++) acc += bf2f(pv0[q]) * eb[q];
        #pragma unroll
        for (int q = 0; q < 8; q++) acc += bf2f(pv1[q]) * eb[8 + q];
    }
    acc += __shfl_xor(acc, 1);
    acc += __shfl_xor(acc, 2);
    acc += __shfl_xor(acc, 4);
    acc += __shfl_xor(acc, 8);
    if (g16 == 0) lg[p] = acc;
    __syncthreads();
    if (tid == 0) {
        float mx = -1e30f;
        for (int q = 0; q < 16; q++) mx = fmaxf(mx, lg[q]);
        float ex[16], z = 0.f;
        for (int q = 0; q < 16; q++) { ex[q] = expf(lg[q] - mx); z += ex[q]; }
        float prob[16];
        for (int q = 0; q < 16; q++) {
            prob[q] = ex[q] / z;
            d_out[2 + b * 16 + q] = prob[q];
        }
        int am = 0; float bv = prob[0];
        for (int q = 1; q < 16; q++) if (prob[q] > bv) { bv = prob[q]; am = q; }
        const int yt = y[b * 2] * 4 + y[b * 2 + 1];
        float z2 = 0.f;
        for (int q = 0; q < 16; q++) z2 += expf(prob[q]);
        const float logp = prob[yt] - logf(z2);
        atomicAdd(&d_out[0], -logp * (1.0f / 2048.0f));
        atomicAdd(&d_out[1], (am == yt) ? (1.0f / 2048.0f) : 0.0f);
    }
}

// ---------------------------------------------------------------------------
extern "C" void kernel_launch(void* const* d_in, const int* in_sizes, int n_in,
                              void* d_out, int out_size, void* d_ws, size_t ws_size,
                              hipStream_t stream) {
    const float* gold_table = (const float*)d_in[0];   // (11,256)
    const float* map_table  = (const float*)d_in[1];   // (128,256)
    const float* conv_w     = (const float*)d_in[2];   // (256,256,3,3)
    const float* a_table    = (const float*)d_in[3];   // (4,32)
    const float* a_W        = (const float*)d_in[4];   // (9,32)
    const float* a_b        = (const float*)d_in[5];   // (9,)
    const int*   gs         = (const int*)d_in[6];     // (2048,4,16)
    const int*   actions    = (const int*)d_in[7];     // (2048,3)
    const int*   lms        = (const int*)d_in[8];     // (2048,4,4,8)
    const int*   y          = (const int*)d_in[9];     // (2048,2)
    float* out = (float*)d_out;

    char* ws = (char*)d_ws;
    int*    cnt  = (int*)(ws + 0);                     // 48 B
    int*    list = (int*)(ws + 256);                   // 98,304 B
    ushort* Wa   = (ushort*)(ws + 131072);             // 4,718,592 B
    ushort* c0   = (ushort*)(ws + 4849664);            // 16,777,216 B each
    ushort* c1   = (ushort*)(ws + 21626880);
    ushort* c2   = (ushort*)(ws + 38404096);
    ushort* c3   = (ushort*)(ws + 55181312);           // end 71,958,528
    (void)in_sizes; (void)n_in; (void)out_size; (void)ws_size;

    k_prep <<<257, 256, 0, stream>>>(conv_w, a_table, a_W, a_b, actions,
                                     cnt, list, Wa, out);
    k_lemb <<<2048, 256, 0, stream>>>(map_table, lms, c0);
    k_conv <<<4096, 256, 0, stream>>>(c0, Wa, cnt, list, 0, c1);
    k_conv <<<4096, 256, 0, stream>>>(c1, Wa, cnt, list, 1, c2);
    k_conv <<<4096, 256, 0, stream>>>(c2, Wa, cnt, list, 2, c3);
    k_final<<<2048, 256, 0, stream>>>(c0, c1, c2, c3, gold_table, gs, y, out);
}

// Round 9
// 423.338 us; speedup vs baseline: 1.6788x; 1.6727x over previous
//
#include <hip/hip_runtime.h>
#include <hip/hip_bf16.h>

typedef __attribute__((ext_vector_type(4))) float f32x4;
typedef __attribute__((ext_vector_type(8))) short short8;

__device__ __forceinline__ float bf2f(ushort u) {
    union { unsigned int u; float f; } x; x.u = ((unsigned int)u) << 16; return x.f;
}
__device__ __forceinline__ ushort f2bf(float f) {
    union { float f; unsigned int u; } x; x.f = f;
    unsigned int u = x.u;
    unsigned int r = (u + 0x7fffu + ((u >> 16) & 1u)) >> 16;  // RNE
    return (ushort)r;
}
__device__ __forceinline__ void gload16(const ushort* g, ushort* l) {
    __builtin_amdgcn_global_load_lds(
        (const __attribute__((address_space(1))) unsigned int*)g,
        (__attribute__((address_space(3))) unsigned int*)l, 16, 0, 0);
}

// ---------------------------------------------------------------------------
// k_front: grid 2048.  EVERY block b: l_emb for sample b -> c0 (bf16).
// Blocks 0..255 additionally repack Wa[a][o][t*256+i] = bf16(m[a]t]*W[o,i,t]).
// Block 256 additionally zeroes cnt/loss/acc and buckets samples by action.
// ---------------------------------------------------------------------------
__global__ __launch_bounds__(256) void k_front(
    const float* __restrict__ conv_w, const float* __restrict__ a_table,
    const float* __restrict__ a_W, const float* __restrict__ a_b,
    const int* __restrict__ actions, const float* __restrict__ mapt,
    const int* __restrict__ lms, int* __restrict__ cnt,
    int* __restrict__ list, ushort* __restrict__ Wa,
    ushort* __restrict__ c0, float* __restrict__ out_head)
{
    const int bid = blockIdx.x, tid = threadIdx.x;

    // ---- l_emb for sample bid (all blocks) ----
    {
        const int e4 = (tid & 63) * 4, pw = tid >> 6;
        #pragma unroll
        for (int pp = 0; pp < 4; ++pp) {
            const int p = pw * 4 + pp;
            const int* lm = lms + (bid * 16 + p) * 8;
            float4 s = make_float4(0.f, 0.f, 0.f, 0.f);
            #pragma unroll
            for (int k = 0; k < 8; ++k) {
                const int idx = lm[k];
                if (idx) {
                    const float4 v = *(const float4*)&mapt[idx * 256 + e4];
                    s.x += v.x; s.y += v.y; s.z += v.z; s.w += v.w;
                }
            }
            ushort o4[4] = { f2bf(s.x), f2bf(s.y), f2bf(s.z), f2bf(s.w) };
            *(uint2*)&c0[(size_t)(bid * 16 + p) * 256 + e4] = *(const uint2*)o4;
        }
    }

    if (bid < 256) {
        __shared__ float ao[4][9];
        __shared__ float m[4][9];
        if (tid < 36) {
            const int a = tid / 9, t = tid % 9;
            float s = a_b[t];
            for (int c = 0; c < 32; c++) s += a_table[a * 32 + c] * a_W[t * 32 + c];
            ao[a][t] = s;
        }
        __syncthreads();
        if (tid < 4) {
            float mx = -1e30f;
            for (int t = 0; t < 9; t++) mx = fmaxf(mx, ao[tid][t]);
            float e[9], z = 0.f;
            for (int t = 0; t < 9; t++) { e[t] = expf(ao[tid][t] - mx); z += e[t]; }
            for (int t = 0; t < 9; t++) m[tid][t] = e[t] / z;
        }
        __syncthreads();
        const int o = bid;
        float w9[9];
        #pragma unroll
        for (int t = 0; t < 9; t++) w9[t] = conv_w[(o * 256 + tid) * 9 + t];
        #pragma unroll
        for (int a = 0; a < 4; a++)
            #pragma unroll
            for (int t = 0; t < 9; t++)
                Wa[(size_t)((a << 8) + o) * 2304 + t * 256 + tid] = f2bf(m[a][t] * w9[t]);
    } else if (bid == 256) {
        if (tid < 12) cnt[tid] = 0;
        if (tid == 0) { out_head[0] = 0.f; out_head[1] = 0.f; }
        __syncthreads();
        for (int it = 0; it < 24; it++) {
            const int idx = it * 256 + tid;          // 0..6143
            const int jj = idx >> 11, b = idx & 2047;
            const int av = actions[b * 3 + jj];
            const int pos = atomicAdd(&cnt[jj * 4 + av], 1);
            list[((jj * 4 + av) << 11) + pos] = b;
        }
    }
}

// ---------------------------------------------------------------------------
// k_conv v5: A via async global_load_lds double-buffer (R5 pipeline) + B
// staged ONCE in LDS (R8).  Steady state: per K-step, one barrier whose
// implicit drain covers only the A-stage (issued one step earlier).
// BM=128 (om half), BN=64 (4 same-action samples), BK=64, 4 waves (2M x 2N),
// wave tile 64x32: 12 ds_read_b128 + 16 MFMA per wave per barrier.
// LDS = 2x16 KB (A, XOR-swizzled) + 34.8 KB (B, XOR-swizzled) = 67.6 KB
// -> 2 blocks/CU (cross-block drain overlap).  Grid 4096 = 8 slots x 512;
// slot = (action, om) for XCD L2 affinity (helpful if round-robin holds).
// ---------------------------------------------------------------------------
__global__ __launch_bounds__(256, 2) void k_conv(
    const ushort* __restrict__ cur, const ushort* __restrict__ Wa,
    const int* __restrict__ cnt, const int* __restrict__ list,
    const int j, ushort* __restrict__ outp)
{
    __shared__ __align__(16) ushort Alds[2][128 * 64];   // 2 x 16 KB
    __shared__ __align__(16) ushort Blds[4 * 17 * 256];  // 34,816 B
    const int tid = threadIdx.x, bid = blockIdx.x;
    const int a = bid & 3, om = (bid >> 2) & 1, grp = bid >> 3;
    const int ca = cnt[j * 4 + a];
    if (grp * 4 >= ca) return;            // uniform exit before any barrier
    const int* la = list + ((j * 4 + a) << 11) + grp * 4;

    const int wid = tid >> 6, lane = tid & 63;
    const int l15 = lane & 15, l4 = lane >> 4;
    const int wm = wid >> 1, wn = wid & 1;

    // ---- stage B: wave wid -> sample slot wid; XOR-swizzled chunks ----
    {
        const int sw = (grp * 4 + wid < ca) ? la[wid] : la[0];
        const ushort* src = cur + (size_t)sw * 4096;
        const int p = lane >> 2, cg = lane & 3;
        ushort* dst = Blds + wid * 4352 + p * 256;
        #pragma unroll
        for (int qq = 0; qq < 8; ++qq) {
            const int c = qq * 4 + cg;
            const uint4 v = *(const uint4*)(src + p * 256 + c * 8);
            *(uint4*)(dst + (c ^ (p & 7)) * 8) = v;
        }
        if (lane < 32) {                       // zero row 16 (padding source)
            const short8 z = {0, 0, 0, 0, 0, 0, 0, 0};
            *(short8*)(Blds + wid * 4352 + 16 * 256 + lane * 8) = z;
        }
    }

    int sid[2]; bool vst[2];
    #pragma unroll
    for (int nf = 0; nf < 2; ++nf) {
        const int sl = wn * 2 + nf;
        vst[nf] = (grp * 4 + sl) < ca;
        sid[nf] = vst[nf] ? la[sl] : 0;
    }

    // ---- A staging: 4 x gload16/thread fills 128x64 bf16 (16 KB) ----
    // unit u = qq*256+tid: row=u>>3, c_lds=u&7; src chunk = c_lds ^ (row&7).
    const ushort* wbase = Wa + (size_t)((a << 8) + om * 128) * 2304;
    const int srow = tid >> 3, sc = tid & 7;
    #define STAGE(buf, k0)                                                     \
        _Pragma("unroll")                                                      \
        for (int qq = 0; qq < 4; ++qq) {                                       \
            const int row = qq * 32 + srow;                                    \
            const int cc = sc ^ (row & 7);                                     \
            gload16(wbase + (size_t)row * 2304 + (k0) + cc * 8,                \
                    &Alds[buf][qq * 2048 + tid * 8]);                          \
        }

    f32x4 acc[4][2];
    #pragma unroll
    for (int mf = 0; mf < 4; ++mf) {
        acc[mf][0] = (f32x4){0.f, 0.f, 0.f, 0.f};
        acc[mf][1] = (f32x4){0.f, 0.f, 0.f, 0.f};
    }

    const int ph = l15 >> 2, pw = l15 & 3;
    const ushort* b0base = Blds + (wn * 2 + 0) * 4352;
    const ushort* b1base = Blds + (wn * 2 + 1) * 4352;

    STAGE(0, 0);
    __syncthreads();           // B staged + A buf0 loaded (drain) + visible

    int cb = 0;
    for (int ks = 0; ks < 36; ++ks) {
        if (ks + 1 < 36) STAGE(cb ^ 1, (ks + 1) * 64);   // async, drains at
                                                         // END-of-iter barrier
        const int t = ks >> 2;                           // 64 | 256
        const int td = (t * 11) >> 5, tm = t - td * 3;   // t/3, t%3
        const int hh = ph + td - 1, ww = pw + tm - 1;
        const bool xv = (hh >= 0) & (hh < 4) & (ww >= 0) & (ww < 4);
        const int brow = xv ? ((hh << 2) + ww) : 16;     // 16 = zero row
        const int rbase = brow * 256, rx = brow & 7;
        const int ch0 = (ks & 3) * 8;                    // chunk base in 256-row

        #pragma unroll
        for (int kf = 0; kf < 2; ++kf) {
            const int bch = ((ch0 + kf * 4 + l4) ^ rx) * 8;
            const short8 bf0 = *(const short8*)(b0base + rbase + bch);
            const short8 bf1 = *(const short8*)(b1base + rbase + bch);
            #pragma unroll
            for (int mf = 0; mf < 4; ++mf) {
                const int rr = wm * 64 + mf * 16 + l15;
                const int acx = ((kf * 4 + l4) ^ (rr & 7)) * 8;
                const short8 af = *(const short8*)&Alds[cb][rr * 64 + acx];
                acc[mf][0] = __builtin_amdgcn_mfma_f32_16x16x32_bf16(
                    af, bf0, acc[mf][0], 0, 0, 0);
                acc[mf][1] = __builtin_amdgcn_mfma_f32_16x16x32_bf16(
                    af, bf1, acc[mf][1], 0, 0, 0);
            }
        }
        __syncthreads();       // drain next-A stage; all reads of cb done
        cb ^= 1;
    }

    // epilogue: C frag col=l15 (=p), row=l4*4+r (=o within 16-tile)
    #pragma unroll
    for (int nf = 0; nf < 2; ++nf) {
        if (!vst[nf]) continue;                      // wave-uniform branch
        const size_t rowb = ((size_t)sid[nf] * 16 + l15) * 256;
        #pragma unroll
        for (int mf = 0; mf < 4; ++mf) {
            const int ob = om * 128 + wm * 64 + mf * 16 + l4 * 4;
            ushort o4[4];
            #pragma unroll
            for (int r = 0; r < 4; r++) o4[r] = f2bf(acc[mf][nf][r]);
            *(uint2*)&outp[rowb + ob] = *(const uint2*)o4;
        }
    }
    #undef STAGE
}

// ---------------------------------------------------------------------------
// k_final: grid B=2048.  emb in-block (17-padded LDS), vectorized bf16 dot,
// shfl_xor 16-lane reduction, softmax chain, loss/acc atomics.
// ---------------------------------------------------------------------------
__global__ __launch_bounds__(256) void k_final(
    const ushort* __restrict__ c0, const ushort* __restrict__ c1,
    const ushort* __restrict__ c2, const ushort* __restrict__ c3,
    const float* __restrict__ gold, const int* __restrict__ gs,
    const int* __restrict__ y, float* __restrict__ d_out)
{
    __shared__ float embl[4][272];
    __shared__ float lg[16];
    const int b = blockIdx.x, tid = threadIdx.x;
    {
        const int s = tid >> 6, e0 = (tid & 63) * 4;
        const int* g = gs + b * 64 + s * 16;
        float4 accv = make_float4(0.f, 0.f, 0.f, 0.f);
        #pragma unroll
        for (int l = 0; l < 16; l++) {
            const float4 v = *(const float4*)&gold[g[l] * 256 + e0];
            accv.x += v.x; accv.y += v.y; accv.z += v.z; accv.w += v.w;
        }
        float* dst = &embl[s][(e0 >> 4) * 17 + (e0 & 15)];
        dst[0] = accv.x; dst[1] = accv.y; dst[2] = accv.z; dst[3] = accv.w;
    }
    __syncthreads();
    const int p = tid >> 4, g16 = tid & 15;
    const ushort* rows[4] = {
        c0 + (size_t)(b * 16 + p) * 256, c1 + (size_t)(b * 16 + p) * 256,
        c2 + (size_t)(b * 16 + p) * 256, c3 + (size_t)(b * 16 + p) * 256 };
    float acc = 0.f;
    #pragma unroll
    for (int s = 0; s < 4; s++) {
        const ushort* row = rows[s] + g16 * 16;
        const uint4 v0 = *(const uint4*)row;
        const uint4 v1 = *(const uint4*)(row + 8);
        const ushort* pv0 = (const ushort*)&v0;
        const ushort* pv1 = (const ushort*)&v1;
        const float* eb = &embl[s][g16 * 17];
        #pragma unroll
        for (int q = 0; q < 8; q++) acc += bf2f(pv0[q]) * eb[q];
        #pragma unroll
        for (int q = 0; q < 8; q++) acc += bf2f(pv1[q]) * eb[8 + q];
    }
    acc += __shfl_xor(acc, 1);
    acc += __shfl_xor(acc, 2);
    acc += __shfl_xor(acc, 4);
    acc += __shfl_xor(acc, 8);
    if (g16 == 0) lg[p] = acc;
    __syncthreads();
    if (tid == 0) {
        float mx = -1e30f;
        for (int q = 0; q < 16; q++) mx = fmaxf(mx, lg[q]);
        float ex[16], z = 0.f;
        for (int q = 0; q < 16; q++) { ex[q] = expf(lg[q] - mx); z += ex[q]; }
        float prob[16];
        for (int q = 0; q < 16; q++) {
            prob[q] = ex[q] / z;
            d_out[2 + b * 16 + q] = prob[q];
        }
        int am = 0; float bv = prob[0];
        for (int q = 1; q < 16; q++) if (prob[q] > bv) { bv = prob[q]; am = q; }
        const int yt = y[b * 2] * 4 + y[b * 2 + 1];
        float z2 = 0.f;
        for (int q = 0; q < 16; q++) z2 += expf(prob[q]);
        const float logp = prob[yt] - logf(z2);
        atomicAdd(&d_out[0], -logp * (1.0f / 2048.0f));
        atomicAdd(&d_out[1], (am == yt) ? (1.0f / 2048.0f) : 0.0f);
    }
}

// ---------------------------------------------------------------------------
extern "C" void kernel_launch(void* const* d_in, const int* in_sizes, int n_in,
                              void* d_out, int out_size, void* d_ws, size_t ws_size,
                              hipStream_t stream) {
    const float* gold_table = (const float*)d_in[0];   // (11,256)
    const float* map_table  = (const float*)d_in[1];   // (128,256)
    const float* conv_w     = (const float*)d_in[2];   // (256,256,3,3)
    const float* a_table    = (const float*)d_in[3];   // (4,32)
    const float* a_W        = (const float*)d_in[4];   // (9,32)
    const float* a_b        = (const float*)d_in[5];   // (9,)
    const int*   gs         = (const int*)d_in[6];     // (2048,4,16)
    const int*   actions    = (const int*)d_in[7];     // (2048,3)
    const int*   lms        = (const int*)d_in[8];     // (2048,4,4,8)
    const int*   y          = (const int*)d_in[9];     // (2048,2)
    float* out = (float*)d_out;

    char* ws = (char*)d_ws;
    int*    cnt  = (int*)(ws + 0);                     // 48 B
    int*    list = (int*)(ws + 256);                   // 98,304 B
    ushort* Wa   = (ushort*)(ws + 131072);             // 4,718,592 B
    ushort* c0   = (ushort*)(ws + 4849664);            // 16,777,216 B each
    ushort* c1   = (ushort*)(ws + 21626880);
    ushort* c2   = (ushort*)(ws + 38404096);
    ushort* c3   = (ushort*)(ws + 55181312);           // end 71,958,528
    (void)in_sizes; (void)n_in; (void)out_size; (void)ws_size;

    k_front<<<2048, 256, 0, stream>>>(conv_w, a_table, a_W, a_b, actions,
                                      map_table, lms, cnt, list, Wa, c0, out);
    k_conv <<<4096, 256, 0, stream>>>(c0, Wa, cnt, list, 0, c1);
    k_conv <<<4096, 256, 0, stream>>>(c1, Wa, cnt, list, 1, c2);
    k_conv <<<4096, 256, 0, stream>>>(c2, Wa, cnt, list, 2, c3);
    k_final<<<2048, 256, 0, stream>>>(c0, c1, c2, c3, gold_table, gs, y, out);
}